// Round 1
// baseline (39132.196 us; speedup 1.0000x reference)
//
#include <hip/hip_runtime.h>
#include <math.h>

#define Bsz 64
#define Tt  1024
#define Dd  256
#define Hh  256
#define TH  512      // entities/slices < T/2, lens >= T/2 -> enc only needed for t < 512
#define G3  768

__device__ __forceinline__ float sigm(float x) { return 1.0f / (1.0f + expf(-x)); }

// Transpose Wih/Whh [768,256] -> [256,768] for coalesced column access. 4 matrices.
__global__ void transpose_k(const float* __restrict__ w0, const float* __restrict__ w1,
                            const float* __restrict__ w2, const float* __restrict__ w3,
                            float* __restrict__ WT) {
    int idx = blockIdx.x * blockDim.x + threadIdx.x;   // over 4*256*768
    int m = idx / (Dd * G3);
    int r = idx - m * (Dd * G3);
    int k = r / G3;
    int jj = r - k * G3;
    const float* s = (m == 0) ? w0 : (m == 1) ? w1 : (m == 2) ? w2 : w3;
    WT[idx] = s[jj * Dd + k];
}

// One WG per (direction, batch-pair). 256 threads, thread j owns output column j.
__global__ __launch_bounds__(256) void scan_k(
    const int* __restrict__ sents, const int* __restrict__ lens,
    const float* __restrict__ emb,
    const float* __restrict__ Q, const float* __restrict__ R,
    const float* __restrict__ bih_f, const float* __restrict__ bhh_f,
    const float* __restrict__ bih_b, const float* __restrict__ bhh_b,
    const float* __restrict__ WT, float* __restrict__ enc)
{
    const int w    = blockIdx.x;          // 0..63
    const int dir  = (w >= 32) ? 1 : 0;
    const int pair = dir ? (w - 32) : w;
    const int b0 = pair * 2, b1 = pair * 2 + 1;
    const int j = threadIdx.x;

    const float* Qd   = Q + dir * Hh * Dd;     // [H,D] row-major: col j coalesced
    const float* Rd   = R + dir * Dd * Hh;     // [D,H] row-major
    const float* WihT = WT + dir * 2 * Dd * G3;
    const float* WhhT = WihT + Dd * G3;
    const float* bih  = dir ? bih_b : bih_f;
    const float* bhh  = dir ? bhh_b : bhh_f;

    __shared__ float2 xs[Dd];    // current x, batches (b0,b1) interleaved
    __shared__ float2 hcs[Hh];   // carried h
    __shared__ float2 hms[Hh];   // mogrified h working buffer

    const int len0 = lens[b0], len1 = lens[b1];
    hcs[j] = make_float2(0.f, 0.f);

    const float bi0 = bih[j], bi1 = bih[j + 256], bi2 = bih[j + 512];
    const float bh0 = bhh[j], bh1 = bhh[j + 256], bh2 = bhh[j + 512];

    int t, tstep, nsteps;
    if (!dir) { t = 0; tstep = 1; nsteps = TH; }                 // fwd: only t<512 observable
    else { int mx = max(len0, len1); t = mx - 1; tstep = -1; nsteps = mx; }  // bwd: h==0 while masked

    __syncthreads();

    for (int s = 0; s < nsteps; ++s, t += tstep) {
        float x0 = emb[(size_t)sents[b0 * Tt + t] * Dd + j];
        float x1 = emb[(size_t)sents[b1 * Tt + t] * Dd + j];

        // A: x = 2*sig(hc @ Q) * x
        float a0 = 0.f, a1 = 0.f;
        const float* wp = Qd + j;
        #pragma unroll 8
        for (int k = 0; k < Hh; ++k) {
            float wv = wp[k * Dd];
            float2 v = hcs[k];
            a0 = fmaf(v.x, wv, a0); a1 = fmaf(v.y, wv, a1);
        }
        x0 *= 2.f * sigm(a0); x1 *= 2.f * sigm(a1);
        xs[j] = make_float2(x0, x1);
        __syncthreads();

        // B: hm = 2*sig(x @ R) * hc
        a0 = 0.f; a1 = 0.f; wp = Rd + j;
        #pragma unroll 8
        for (int k = 0; k < Dd; ++k) {
            float wv = wp[k * Hh];
            float2 v = xs[k];
            a0 = fmaf(v.x, wv, a0); a1 = fmaf(v.y, wv, a1);
        }
        float2 hcj = hcs[j];
        float hm0 = 2.f * sigm(a0) * hcj.x;
        float hm1 = 2.f * sigm(a1) * hcj.y;
        hms[j] = make_float2(hm0, hm1);
        __syncthreads();

        // C: x = 2*sig(hm @ Q) * x
        a0 = 0.f; a1 = 0.f; wp = Qd + j;
        #pragma unroll 8
        for (int k = 0; k < Hh; ++k) {
            float wv = wp[k * Dd];
            float2 v = hms[k];
            a0 = fmaf(v.x, wv, a0); a1 = fmaf(v.y, wv, a1);
        }
        x0 *= 2.f * sigm(a0); x1 *= 2.f * sigm(a1);
        xs[j] = make_float2(x0, x1);
        __syncthreads();

        // D: hm = 2*sig(x @ R) * hm
        a0 = 0.f; a1 = 0.f; wp = Rd + j;
        #pragma unroll 8
        for (int k = 0; k < Dd; ++k) {
            float wv = wp[k * Hh];
            float2 v = xs[k];
            a0 = fmaf(v.x, wv, a0); a1 = fmaf(v.y, wv, a1);
        }
        hm0 *= 2.f * sigm(a0); hm1 *= 2.f * sigm(a1);
        hms[j] = make_float2(hm0, hm1);
        __syncthreads();

        // E: gi = x@Wih^T + bih ; gh = hm@Whh^T + bhh   (cols j, j+256, j+512)
        float ir0 = bi0, ir1 = bi0, iz0 = bi1, iz1 = bi1, in0 = bi2, in1 = bi2;
        float hr0 = bh0, hr1 = bh0, hz0 = bh1, hz1 = bh1, hn0 = bh2, hn1 = bh2;
        const float* wi = WihT + j;
        const float* wh = WhhT + j;
        #pragma unroll 4
        for (int k = 0; k < Dd; ++k) {
            float2 xv = xs[k];
            float2 hv = hms[k];
            float w0v = wi[k * G3], w1v = wi[k * G3 + 256], w2v = wi[k * G3 + 512];
            float u0v = wh[k * G3], u1v = wh[k * G3 + 256], u2v = wh[k * G3 + 512];
            ir0 = fmaf(xv.x, w0v, ir0); ir1 = fmaf(xv.y, w0v, ir1);
            iz0 = fmaf(xv.x, w1v, iz0); iz1 = fmaf(xv.y, w1v, iz1);
            in0 = fmaf(xv.x, w2v, in0); in1 = fmaf(xv.y, w2v, in1);
            hr0 = fmaf(hv.x, u0v, hr0); hr1 = fmaf(hv.y, u0v, hr1);
            hz0 = fmaf(hv.x, u1v, hz0); hz1 = fmaf(hv.y, u1v, hz1);
            hn0 = fmaf(hv.x, u2v, hn0); hn1 = fmaf(hv.y, u2v, hn1);
        }
        float r0 = sigm(ir0 + hr0), r1 = sigm(ir1 + hr1);
        float z0 = sigm(iz0 + hz0), z1 = sigm(iz1 + hz1);
        float n0 = tanhf(in0 + r0 * hn0), n1 = tanhf(in1 + r1 * hn1);
        float u0 = (1.f - z0) * n0 + z0 * hm0;
        float u1 = (1.f - z1) * n1 + z1 * hm1;

        bool m0 = (t < len0), m1 = (t < len1);
        hcj = hcs[j];
        hcs[j] = make_float2(m0 ? u0 : hcj.x, m1 ? u1 : hcj.y);
        if (t < TH) {
            // fwd and bwd each add exactly once per element; float add is commutative
            atomicAdd(&enc[((size_t)b0 * TH + t) * Hh + j], m0 ? u0 : 0.f);
            atomicAdd(&enc[((size_t)b1 * TH + t) * Hh + j], m1 ? u1 : 0.f);
        }
        __syncthreads();
    }
}

// One WG per batch element. Reproduces gate_attention + attention + dense exactly.
__global__ __launch_bounds__(256) void epi_k(
    const float* __restrict__ enc,
    const int* __restrict__ entities, const int* __restrict__ slices,
    const float* __restrict__ slice_lens,
    const int* __restrict__ entity_masks, const int* __restrict__ slice_masks,
    const float* __restrict__ ent_W, const float* __restrict__ ent_b,
    const float* __restrict__ att_w,
    const float* __restrict__ dense_W, const float* __restrict__ dense_b,
    float* __restrict__ out)
{
    const int b = blockIdx.x;
    const int j = threadIdx.x;
    const int wave = j >> 6, lane = j & 63;

    __shared__ float ee[8][256];
    __shared__ float p[256];
    __shared__ float rela[256];
    __shared__ float sc[264];
    __shared__ float red[4];
    __shared__ float aw[256];
    __shared__ int   spos[256];

    aw[j]   = att_w[j];
    spos[j] = slices[b * 256 + j];
    #pragma unroll
    for (int e = 0; e < 8; ++e)
        ee[e][j] = enc[((size_t)b * TH + entities[b * 8 + e]) * Hh + j];
    __syncthreads();

    // ew[e] = ee[e] . ent_W + ent_b, masked softmax over E=8
    float entWj = ent_W[j];
    for (int e = 0; e < 8; ++e) {
        float v = ee[e][j] * entWj;
        #pragma unroll
        for (int o = 32; o > 0; o >>= 1) v += __shfl_down(v, o);
        if (lane == 0) red[wave] = v;
        __syncthreads();
        if (j == 0) sc[e] = red[0] + red[1] + red[2] + red[3] + ent_b[0];
        __syncthreads();
    }
    float mx = -INFINITY;
    float ewv[8];
    #pragma unroll
    for (int e = 0; e < 8; ++e) {
        float v = entity_masks[b * 8 + e] ? sc[e] : -INFINITY;
        ewv[e] = v; mx = fmaxf(mx, v);
    }
    float den = 0.f;
    #pragma unroll
    for (int e = 0; e < 8; ++e) {
        ewv[e] = entity_masks[b * 8 + e] ? expf(ewv[e] - mx) : 0.f;
        den += ewv[e];
    }
    float accp = 0.f;
    #pragma unroll
    for (int e = 0; e < 8; ++e) accp += (ewv[e] / den) * ee[e][j];
    p[j] = tanhf(accp);
    __syncthreads();

    // words[s] = es[s] . p   (wave per slice)
    for (int s0 = wave; s0 < 256; s0 += 4) {
        const float* row = enc + ((size_t)b * TH + spos[s0]) * Hh;
        float v = 0.f;
        #pragma unroll
        for (int i = 0; i < 4; ++i) { int c = lane + 64 * i; v += row[c] * p[c]; }
        #pragma unroll
        for (int o = 32; o > 0; o >>= 1) v += __shfl_down(v, o);
        if (lane == 0) sc[s0] = v;
    }
    __syncthreads();

    // masked softmax over S=256 -> ww -> rela
    float sl  = slice_lens[b];
    int   smk = slice_masks[b * 256 + j];
    float wv  = smk ? sc[j] : -INFINITY;
    float bm = wv;
    #pragma unroll
    for (int o = 32; o > 0; o >>= 1) bm = fmaxf(bm, __shfl_down(bm, o));
    __syncthreads();
    if (lane == 0) red[wave] = bm;
    __syncthreads();
    bm = fmaxf(fmaxf(red[0], red[1]), fmaxf(red[2], red[3]));
    float ex = smk ? expf(wv - bm) : 0.f;
    float sm = ex;
    #pragma unroll
    for (int o = 32; o > 0; o >>= 1) sm += __shfl_down(sm, o);
    __syncthreads();
    if (lane == 0) red[wave] = sm;
    __syncthreads();
    sm = red[0] + red[1] + red[2] + red[3];
    float ww = ex / sm * sl;
    float rl = (ww > 0.05f) ? (ww / sl) : 0.f;   // BETA = 0.05
    float rm = rl;
    #pragma unroll
    for (int o = 32; o > 0; o >>= 1) rm = fmaxf(rm, __shfl_down(rm, o));
    __syncthreads();
    if (lane == 0) red[wave] = rm;
    __syncthreads();
    rm = fmaxf(fmaxf(red[0], red[1]), fmaxf(red[2], red[3]));
    rl = rl / rm;
    rela[j] = rl;
    __syncthreads();

    // a[n] = tanh(Hcat[n]) . att_w, n in [0,264): first 8 = ee, rest = rela*es
    for (int n = wave; n < 264; n += 4) {
        float v = 0.f;
        if (n < 8) {
            #pragma unroll
            for (int i = 0; i < 4; ++i) { int c = lane + 64 * i; v += tanhf(ee[n][c]) * aw[c]; }
        } else {
            int s0 = n - 8;
            const float* row = enc + ((size_t)b * TH + spos[s0]) * Hh;
            float rl2 = rela[s0];
            #pragma unroll
            for (int i = 0; i < 4; ++i) { int c = lane + 64 * i; v += tanhf(rl2 * row[c]) * aw[c]; }
        }
        #pragma unroll
        for (int o = 32; o > 0; o >>= 1) v += __shfl_down(v, o);
        if (lane == 0) sc[n] = v;
    }
    __syncthreads();

    // softmax over a with where(a==0 -> -inf); thread j owns n=j and (j<8) n=256+j
    float a1 = sc[j];       a1 = (a1 == 0.f) ? -INFINITY : a1;
    float a2 = (j < 8) ? sc[256 + j] : -INFINITY;
    if (a2 == 0.f) a2 = -INFINITY;
    float am = fmaxf(a1, a2);
    #pragma unroll
    for (int o = 32; o > 0; o >>= 1) am = fmaxf(am, __shfl_down(am, o));
    __syncthreads();
    if (lane == 0) red[wave] = am;
    __syncthreads();
    am = fmaxf(fmaxf(red[0], red[1]), fmaxf(red[2], red[3]));
    float e1 = (a1 == -INFINITY) ? 0.f : expf(a1 - am);
    float e2 = (a2 == -INFINITY) ? 0.f : expf(a2 - am);
    float esum = e1 + e2;
    #pragma unroll
    for (int o = 32; o > 0; o >>= 1) esum += __shfl_down(esum, o);
    __syncthreads();
    if (lane == 0) red[wave] = esum;
    __syncthreads();
    esum = red[0] + red[1] + red[2] + red[3];
    __syncthreads();
    sc[j] = e1 / esum;
    if (j < 8) sc[256 + j] = e2 / esum;
    __syncthreads();

    // att[j] = sum_n score[n] * Hcat[n][j]
    float att = 0.f;
    #pragma unroll
    for (int n = 0; n < 8; ++n) att += sc[n] * ee[n][j];
    for (int s0 = 0; s0 < 256; ++s0) {
        float scn = sc[8 + s0];
        if (scn > 0.f)
            att += scn * rela[s0] * enc[((size_t)b * TH + spos[s0]) * Hh + j];
    }
    float ta = tanhf(att);

    // out[l] = tanh(att) . dense_W[l] + dense_b[l]
    for (int l = 0; l < 19; ++l) {
        float v = ta * dense_W[l * 256 + j];
        #pragma unroll
        for (int o = 32; o > 0; o >>= 1) v += __shfl_down(v, o);
        __syncthreads();
        if (lane == 0) red[wave] = v;
        __syncthreads();
        if (j == 0) out[b * 19 + l] = red[0] + red[1] + red[2] + red[3] + dense_b[l];
    }
}

extern "C" void kernel_launch(void* const* d_in, const int* in_sizes, int n_in,
                              void* d_out, int out_size, void* d_ws, size_t ws_size,
                              hipStream_t stream) {
    const int*   sents        = (const int*)d_in[0];
    const int*   lens         = (const int*)d_in[1];
    const int*   entities     = (const int*)d_in[2];
    const int*   slices       = (const int*)d_in[3];
    const float* slice_lens   = (const float*)d_in[4];
    const int*   entity_masks = (const int*)d_in[5];
    const int*   slice_masks  = (const int*)d_in[6];
    const float* emb          = (const float*)d_in[7];
    const float* Q            = (const float*)d_in[8];
    const float* R            = (const float*)d_in[9];
    const float* Wih_f        = (const float*)d_in[10];
    const float* Whh_f        = (const float*)d_in[11];
    const float* bih_f        = (const float*)d_in[12];
    const float* bhh_f        = (const float*)d_in[13];
    const float* Wih_b        = (const float*)d_in[14];
    const float* Whh_b        = (const float*)d_in[15];
    const float* bih_b        = (const float*)d_in[16];
    const float* bhh_b        = (const float*)d_in[17];
    const float* ent_W        = (const float*)d_in[18];
    const float* ent_b        = (const float*)d_in[19];
    const float* att_w        = (const float*)d_in[20];
    const float* dense_W      = (const float*)d_in[21];
    const float* dense_b      = (const float*)d_in[22];

    // ws layout: enc [64][512][256] f32 (33.5MB) | WT 4*[256][768] f32 (3.1MB)
    float* enc = (float*)d_ws;
    float* WT  = enc + (size_t)Bsz * TH * Hh;

    hipMemsetAsync(enc, 0, (size_t)Bsz * TH * Hh * sizeof(float), stream);
    transpose_k<<<(4 * Dd * G3) / 256, 256, 0, stream>>>(Wih_f, Whh_f, Wih_b, Whh_b, WT);
    scan_k<<<64, 256, 0, stream>>>(sents, lens, emb, Q, R,
                                   bih_f, bhh_f, bih_b, bhh_b, WT, enc);
    epi_k<<<64, 256, 0, stream>>>(enc, entities, slices, slice_lens,
                                  entity_masks, slice_masks, ent_W, ent_b,
                                  att_w, dense_W, dense_b, (float*)d_out);
}

// Round 2
// 29821.597 us; speedup vs baseline: 1.3122x; 1.3122x over previous
//
#include <hip/hip_runtime.h>
#include <math.h>

#define Bsz 64
#define Tt  1024
#define Dd  256
#define Hh  256
#define TH  512      // entities/slices < T/2, lens >= T/2 -> enc only needed for t < 512
#define G3  768

__device__ __forceinline__ float sigm(float x) { return 1.0f / (1.0f + expf(-x)); }

// Pack weights into [k4][col] float4 blocks: element (k4, col) = W[4k4+0..3][col].
// Qp/Rp: per dir [64][256] f4. Wip/Whp: per dir [64][768] f4 (from [col][k] row-major).
__global__ void pack_k(const float* __restrict__ Q, const float* __restrict__ R,
                       const float* __restrict__ Wih_f, const float* __restrict__ Whh_f,
                       const float* __restrict__ Wih_b, const float* __restrict__ Whh_b,
                       float4* __restrict__ Qp, float4* __restrict__ Rp,
                       float4* __restrict__ Wip, float4* __restrict__ Whp)
{
    int idx = blockIdx.x * 256 + threadIdx.x;
    if (idx < 32768) {                       // 2 dirs * 64 k4 * 256 cols
        int d = idx >> 14, r = idx & 16383;
        int k4 = r >> 8, j = r & 255;
        const float* S = Q + d * 65536;
        Qp[idx] = make_float4(S[(4*k4+0)*256 + j], S[(4*k4+1)*256 + j],
                              S[(4*k4+2)*256 + j], S[(4*k4+3)*256 + j]);
        S = R + d * 65536;
        Rp[idx] = make_float4(S[(4*k4+0)*256 + j], S[(4*k4+1)*256 + j],
                              S[(4*k4+2)*256 + j], S[(4*k4+3)*256 + j]);
    }
    if (idx < 98304) {                       // 2 dirs * 64 k4 * 768 cols
        int d = idx / 49152, r = idx % 49152;
        int k4 = r / 768, col = r % 768;
        const float* Wi = d ? Wih_b : Wih_f;
        const float* Wh = d ? Whh_b : Whh_f;
        Wip[idx] = *(const float4*)(Wi + col * 256 + 4 * k4);   // contiguous in source
        Whp[idx] = *(const float4*)(Wh + col * 256 + 4 * k4);
    }
}

// One WG of 512 threads per (direction, batch-pair).
// Mogrify matvecs: 8-way k-split, 4 cols/lane. GRU: 4-way k-split, 12 cols/lane.
__global__ __launch_bounds__(512) void scan_k(
    const int* __restrict__ sents, const int* __restrict__ lens,
    const float* __restrict__ emb,
    const float* __restrict__ bih_f, const float* __restrict__ bhh_f,
    const float* __restrict__ bih_b, const float* __restrict__ bhh_b,
    const float4* __restrict__ Qp4, const float4* __restrict__ Rp4,
    const float4* __restrict__ Wip4, const float4* __restrict__ Whp4,
    float* __restrict__ enc)
{
    const int w = blockIdx.x;                  // 0..63
    const int dir  = ((w & 7) >= 4) ? 1 : 0;   // dir constant per XCD residue class
    const int pair = (w >> 3) * 4 + (w & 3);   // 0..31, unique per dir
    const int b0 = pair * 2, b1 = b0 + 1;
    const int tid = threadIdx.x;
    const int j   = tid & 255;                 // finalize column (tid<256)
    const int ks8 = tid >> 6;                  // 0..7  k-slice for mogrify
    const int l64 = tid & 63;                  // lane col base for mogrify
    const int ks4 = tid >> 7;                  // 0..3  k-slice for GRU
    const int rE  = tid & 127;
    const int mh  = (rE >> 6) & 1;             // 0: Wih(x), 1: Whh(hm) — wave-uniform
    const int l2  = rE & 63;

    const float4* Qp  = Qp4  + dir * 16384;    // [k4][256]
    const float4* Rp  = Rp4  + dir * 16384;
    const float4* Wip = Wip4 + dir * 49152;    // [k4][768]
    const float4* Whp = Whp4 + dir * 49152;
    const float* bih = dir ? bih_b : bih_f;
    const float* bhh = dir ? bhh_b : bhh_f;

    __shared__ __align__(16) float2 xs[256], hcs[256], hms[256];    // 6 KB
    __shared__ __align__(16) float2 redbuf[4 * 768 * 2];            // 48 KB, overlaid
    float2 (*part)[256] = (float2(*)[256])redbuf;                   // [8][256] (A-D)
    float2 (*giP)[768]  = (float2(*)[768])redbuf;                   // [4][768] (E)
    float2 (*ghP)[768]  = (float2(*)[768])(redbuf + 4 * 768);       // [4][768] (E)

    const int len0 = lens[b0], len1 = lens[b1];
    if (tid < 256) hcs[tid] = make_float2(0.f, 0.f);

    const float bi0 = bih[j], bi1 = bih[j + 256], bi2 = bih[j + 512];
    const float bh0 = bhh[j], bh1 = bhh[j + 256], bh2 = bhh[j + 512];

    int t, tstep, nsteps;
    if (!dir) { t = 0; tstep = 1; nsteps = TH; }                      // fwd: only t<512 observable
    else { int mx = max(len0, len1); t = mx - 1; tstep = -1; nsteps = mx; } // bwd: h==0 while masked

    float x0 = 0.f, x1 = 0.f, hm0 = 0.f, hm1 = 0.f;
    __syncthreads();

    // 8-way-k-split partial matvec over a 256-col packed matrix.
    auto mog_partial = [&](const float4* __restrict__ M, const float2* IN) {
        float a00=0,a01=0,a10=0,a11=0,a20=0,a21=0,a30=0,a31=0;
        const float4* Lv = (const float4*)IN;
        const int k4b = ks8 * 8;
        #pragma unroll 4
        for (int i = 0; i < 8; ++i) {
            const int k4 = k4b + i;
            const float4 v01 = Lv[2*k4], v23 = Lv[2*k4+1];
            const float4 w0 = M[k4*256 + l64];
            const float4 w1 = M[k4*256 + l64 + 64];
            const float4 w2 = M[k4*256 + l64 + 128];
            const float4 w3 = M[k4*256 + l64 + 192];
            a00=fmaf(w0.x,v01.x,a00); a00=fmaf(w0.y,v01.z,a00); a00=fmaf(w0.z,v23.x,a00); a00=fmaf(w0.w,v23.z,a00);
            a01=fmaf(w0.x,v01.y,a01); a01=fmaf(w0.y,v01.w,a01); a01=fmaf(w0.z,v23.y,a01); a01=fmaf(w0.w,v23.w,a01);
            a10=fmaf(w1.x,v01.x,a10); a10=fmaf(w1.y,v01.z,a10); a10=fmaf(w1.z,v23.x,a10); a10=fmaf(w1.w,v23.z,a10);
            a11=fmaf(w1.x,v01.y,a11); a11=fmaf(w1.y,v01.w,a11); a11=fmaf(w1.z,v23.y,a11); a11=fmaf(w1.w,v23.w,a11);
            a20=fmaf(w2.x,v01.x,a20); a20=fmaf(w2.y,v01.z,a20); a20=fmaf(w2.z,v23.x,a20); a20=fmaf(w2.w,v23.z,a20);
            a21=fmaf(w2.x,v01.y,a21); a21=fmaf(w2.y,v01.w,a21); a21=fmaf(w2.z,v23.y,a21); a21=fmaf(w2.w,v23.w,a21);
            a30=fmaf(w3.x,v01.x,a30); a30=fmaf(w3.y,v01.z,a30); a30=fmaf(w3.z,v23.x,a30); a30=fmaf(w3.w,v23.z,a30);
            a31=fmaf(w3.x,v01.y,a31); a31=fmaf(w3.y,v01.w,a31); a31=fmaf(w3.z,v23.y,a31); a31=fmaf(w3.w,v23.w,a31);
        }
        part[ks8][l64      ] = make_float2(a00, a01);
        part[ks8][l64 +  64] = make_float2(a10, a11);
        part[ks8][l64 + 128] = make_float2(a20, a21);
        part[ks8][l64 + 192] = make_float2(a30, a31);
    };
    auto psum = [&]() -> float2 {             // finalize-thread 8-way partial sum (col j)
        float s0 = 0.f, s1 = 0.f;
        #pragma unroll
        for (int p = 0; p < 8; ++p) { float2 v = part[p][j]; s0 += v.x; s1 += v.y; }
        return make_float2(s0, s1);
    };

    for (int s = 0; s < nsteps; ++s, t += tstep) {
        if (tid < 256) {                      // prefetch x; overlaps stage-A k-loop
            x0 = emb[(size_t)sents[b0 * Tt + t] * 256 + j];
            x1 = emb[(size_t)sents[b1 * Tt + t] * 256 + j];
        }
        // A: x = 2*sig(hc @ Q) * x
        mog_partial(Qp, hcs);
        __syncthreads();
        if (tid < 256) {
            float2 sv = psum();
            x0 *= 2.f * sigm(sv.x);  x1 *= 2.f * sigm(sv.y);
            xs[j] = make_float2(x0, x1);
        }
        __syncthreads();
        // B: hm = 2*sig(x @ R) * hc
        mog_partial(Rp, xs);
        __syncthreads();
        if (tid < 256) {
            float2 sv = psum();
            float2 hcj = hcs[j];
            hm0 = 2.f * sigm(sv.x) * hcj.x;  hm1 = 2.f * sigm(sv.y) * hcj.y;
            hms[j] = make_float2(hm0, hm1);
        }
        __syncthreads();
        // C: x = 2*sig(hm @ Q) * x
        mog_partial(Qp, hms);
        __syncthreads();
        if (tid < 256) {
            float2 sv = psum();
            x0 *= 2.f * sigm(sv.x);  x1 *= 2.f * sigm(sv.y);
            xs[j] = make_float2(x0, x1);
        }
        __syncthreads();
        // D: hm = 2*sig(x @ R) * hm
        mog_partial(Rp, xs);
        __syncthreads();
        if (tid < 256) {
            float2 sv = psum();
            hm0 *= 2.f * sigm(sv.x);  hm1 *= 2.f * sigm(sv.y);
            hms[j] = make_float2(hm0, hm1);
        }
        __syncthreads();
        // E: gi = x@Wih^T, gh = hm@Whh^T  (4-way k-split, 12 cols/lane, per-mat waves)
        {
            const float4* Wp = mh ? Whp : Wip;
            const float4* Lv = mh ? (const float4*)hms : (const float4*)xs;
            float a[12][2];
            #pragma unroll
            for (int c = 0; c < 12; ++c) { a[c][0] = 0.f; a[c][1] = 0.f; }
            const int k4b = ks4 * 16;
            for (int i = 0; i < 16; ++i) {
                const int k4 = k4b + i;
                const float4 v01 = Lv[2*k4], v23 = Lv[2*k4+1];
                #pragma unroll
                for (int c = 0; c < 12; ++c) {
                    const float4 wv = Wp[k4*768 + l2 + 64*c];
                    a[c][0]=fmaf(wv.x,v01.x,a[c][0]); a[c][0]=fmaf(wv.y,v01.z,a[c][0]);
                    a[c][0]=fmaf(wv.z,v23.x,a[c][0]); a[c][0]=fmaf(wv.w,v23.z,a[c][0]);
                    a[c][1]=fmaf(wv.x,v01.y,a[c][1]); a[c][1]=fmaf(wv.y,v01.w,a[c][1]);
                    a[c][1]=fmaf(wv.z,v23.y,a[c][1]); a[c][1]=fmaf(wv.w,v23.w,a[c][1]);
                }
            }
            float2 (*dst)[768] = mh ? ghP : giP;
            #pragma unroll
            for (int c = 0; c < 12; ++c)
                dst[ks4][l2 + 64*c] = make_float2(a[c][0], a[c][1]);
        }
        __syncthreads();
        if (tid < 256) {
            float gix[3], giy[3], ghx[3], ghy[3];
            #pragma unroll
            for (int g = 0; g < 3; ++g) {
                float s0=0,s1=0,t0=0,t1=0;
                #pragma unroll
                for (int p = 0; p < 4; ++p) {
                    float2 vi = giP[p][j + 256*g]; s0 += vi.x; s1 += vi.y;
                    float2 vh = ghP[p][j + 256*g]; t0 += vh.x; t1 += vh.y;
                }
                gix[g]=s0; giy[g]=s1; ghx[g]=t0; ghy[g]=t1;
            }
            float r0 = sigm(gix[0]+bi0 + ghx[0]+bh0), r1 = sigm(giy[0]+bi0 + ghy[0]+bh0);
            float z0 = sigm(gix[1]+bi1 + ghx[1]+bh1), z1 = sigm(giy[1]+bi1 + ghy[1]+bh1);
            float n0 = tanhf(gix[2]+bi2 + r0*(ghx[2]+bh2));
            float n1 = tanhf(giy[2]+bi2 + r1*(ghy[2]+bh2));
            float u0 = (1.f - z0) * n0 + z0 * hm0;
            float u1 = (1.f - z1) * n1 + z1 * hm1;
            bool m0 = (t < len0), m1 = (t < len1);
            float2 hcj = hcs[j];
            hcs[j] = make_float2(m0 ? u0 : hcj.x, m1 ? u1 : hcj.y);
            if (t < TH) {
                atomicAdd(&enc[((size_t)b0 * TH + t) * Hh + j], m0 ? u0 : 0.f);
                atomicAdd(&enc[((size_t)b1 * TH + t) * Hh + j], m1 ? u1 : 0.f);
            }
        }
        __syncthreads();
    }
}

// One WG per batch element. Reproduces gate_attention + attention + dense exactly.
__global__ __launch_bounds__(256) void epi_k(
    const float* __restrict__ enc,
    const int* __restrict__ entities, const int* __restrict__ slices,
    const float* __restrict__ slice_lens,
    const int* __restrict__ entity_masks, const int* __restrict__ slice_masks,
    const float* __restrict__ ent_W, const float* __restrict__ ent_b,
    const float* __restrict__ att_w,
    const float* __restrict__ dense_W, const float* __restrict__ dense_b,
    float* __restrict__ out)
{
    const int b = blockIdx.x;
    const int j = threadIdx.x;
    const int wave = j >> 6, lane = j & 63;

    __shared__ float ee[8][256];
    __shared__ float p[256];
    __shared__ float rela[256];
    __shared__ float sc[264];
    __shared__ float red[4];
    __shared__ float aw[256];
    __shared__ int   spos[256];

    aw[j]   = att_w[j];
    spos[j] = slices[b * 256 + j];
    #pragma unroll
    for (int e = 0; e < 8; ++e)
        ee[e][j] = enc[((size_t)b * TH + entities[b * 8 + e]) * Hh + j];
    __syncthreads();

    float entWj = ent_W[j];
    for (int e = 0; e < 8; ++e) {
        float v = ee[e][j] * entWj;
        #pragma unroll
        for (int o = 32; o > 0; o >>= 1) v += __shfl_down(v, o);
        if (lane == 0) red[wave] = v;
        __syncthreads();
        if (j == 0) sc[e] = red[0] + red[1] + red[2] + red[3] + ent_b[0];
        __syncthreads();
    }
    float mx = -INFINITY;
    float ewv[8];
    #pragma unroll
    for (int e = 0; e < 8; ++e) {
        float v = entity_masks[b * 8 + e] ? sc[e] : -INFINITY;
        ewv[e] = v; mx = fmaxf(mx, v);
    }
    float den = 0.f;
    #pragma unroll
    for (int e = 0; e < 8; ++e) {
        ewv[e] = entity_masks[b * 8 + e] ? expf(ewv[e] - mx) : 0.f;
        den += ewv[e];
    }
    float accp = 0.f;
    #pragma unroll
    for (int e = 0; e < 8; ++e) accp += (ewv[e] / den) * ee[e][j];
    p[j] = tanhf(accp);
    __syncthreads();

    for (int s0 = wave; s0 < 256; s0 += 4) {
        const float* row = enc + ((size_t)b * TH + spos[s0]) * Hh;
        float v = 0.f;
        #pragma unroll
        for (int i = 0; i < 4; ++i) { int c = lane + 64 * i; v += row[c] * p[c]; }
        #pragma unroll
        for (int o = 32; o > 0; o >>= 1) v += __shfl_down(v, o);
        if (lane == 0) sc[s0] = v;
    }
    __syncthreads();

    float sl  = slice_lens[b];
    int   smk = slice_masks[b * 256 + j];
    float wv  = smk ? sc[j] : -INFINITY;
    float bm = wv;
    #pragma unroll
    for (int o = 32; o > 0; o >>= 1) bm = fmaxf(bm, __shfl_down(bm, o));
    __syncthreads();
    if (lane == 0) red[wave] = bm;
    __syncthreads();
    bm = fmaxf(fmaxf(red[0], red[1]), fmaxf(red[2], red[3]));
    float ex = smk ? expf(wv - bm) : 0.f;
    float sm = ex;
    #pragma unroll
    for (int o = 32; o > 0; o >>= 1) sm += __shfl_down(sm, o);
    __syncthreads();
    if (lane == 0) red[wave] = sm;
    __syncthreads();
    sm = red[0] + red[1] + red[2] + red[3];
    float ww = ex / sm * sl;
    float rl = (ww > 0.05f) ? (ww / sl) : 0.f;   // BETA = 0.05
    float rm = rl;
    #pragma unroll
    for (int o = 32; o > 0; o >>= 1) rm = fmaxf(rm, __shfl_down(rm, o));
    __syncthreads();
    if (lane == 0) red[wave] = rm;
    __syncthreads();
    rm = fmaxf(fmaxf(red[0], red[1]), fmaxf(red[2], red[3]));
    rl = rl / rm;
    rela[j] = rl;
    __syncthreads();

    for (int n = wave; n < 264; n += 4) {
        float v = 0.f;
        if (n < 8) {
            #pragma unroll
            for (int i = 0; i < 4; ++i) { int c = lane + 64 * i; v += tanhf(ee[n][c]) * aw[c]; }
        } else {
            int s0 = n - 8;
            const float* row = enc + ((size_t)b * TH + spos[s0]) * Hh;
            float rl2 = rela[s0];
            #pragma unroll
            for (int i = 0; i < 4; ++i) { int c = lane + 64 * i; v += tanhf(rl2 * row[c]) * aw[c]; }
        }
        #pragma unroll
        for (int o = 32; o > 0; o >>= 1) v += __shfl_down(v, o);
        if (lane == 0) sc[n] = v;
    }
    __syncthreads();

    float a1 = sc[j];       a1 = (a1 == 0.f) ? -INFINITY : a1;
    float a2 = (j < 8) ? sc[256 + j] : -INFINITY;
    if (a2 == 0.f) a2 = -INFINITY;
    float am = fmaxf(a1, a2);
    #pragma unroll
    for (int o = 32; o > 0; o >>= 1) am = fmaxf(am, __shfl_down(am, o));
    __syncthreads();
    if (lane == 0) red[wave] = am;
    __syncthreads();
    am = fmaxf(fmaxf(red[0], red[1]), fmaxf(red[2], red[3]));
    float e1 = (a1 == -INFINITY) ? 0.f : expf(a1 - am);
    float e2 = (a2 == -INFINITY) ? 0.f : expf(a2 - am);
    float esum = e1 + e2;
    #pragma unroll
    for (int o = 32; o > 0; o >>= 1) esum += __shfl_down(esum, o);
    __syncthreads();
    if (lane == 0) red[wave] = esum;
    __syncthreads();
    esum = red[0] + red[1] + red[2] + red[3];
    __syncthreads();
    sc[j] = e1 / esum;
    if (j < 8) sc[256 + j] = e2 / esum;
    __syncthreads();

    float att = 0.f;
    #pragma unroll
    for (int n = 0; n < 8; ++n) att += sc[n] * ee[n][j];
    for (int s0 = 0; s0 < 256; ++s0) {
        float scn = sc[8 + s0];
        if (scn > 0.f)
            att += scn * rela[s0] * enc[((size_t)b * TH + spos[s0]) * Hh + j];
    }
    float ta = tanhf(att);

    for (int l = 0; l < 19; ++l) {
        float v = ta * dense_W[l * 256 + j];
        #pragma unroll
        for (int o = 32; o > 0; o >>= 1) v += __shfl_down(v, o);
        __syncthreads();
        if (lane == 0) red[wave] = v;
        __syncthreads();
        if (j == 0) out[b * 19 + l] = red[0] + red[1] + red[2] + red[3] + dense_b[l];
    }
}

extern "C" void kernel_launch(void* const* d_in, const int* in_sizes, int n_in,
                              void* d_out, int out_size, void* d_ws, size_t ws_size,
                              hipStream_t stream) {
    (void)in_sizes; (void)n_in; (void)out_size; (void)ws_size;
    const int*   sents        = (const int*)d_in[0];
    const int*   lens         = (const int*)d_in[1];
    const int*   entities     = (const int*)d_in[2];
    const int*   slices       = (const int*)d_in[3];
    const float* slice_lens   = (const float*)d_in[4];
    const int*   entity_masks = (const int*)d_in[5];
    const int*   slice_masks  = (const int*)d_in[6];
    const float* emb          = (const float*)d_in[7];
    const float* Q            = (const float*)d_in[8];
    const float* R            = (const float*)d_in[9];
    const float* Wih_f        = (const float*)d_in[10];
    const float* Whh_f        = (const float*)d_in[11];
    const float* bih_f        = (const float*)d_in[12];
    const float* bhh_f        = (const float*)d_in[13];
    const float* Wih_b        = (const float*)d_in[14];
    const float* Whh_b        = (const float*)d_in[15];
    const float* bih_b        = (const float*)d_in[16];
    const float* bhh_b        = (const float*)d_in[17];
    const float* ent_W        = (const float*)d_in[18];
    const float* ent_b        = (const float*)d_in[19];
    const float* att_w        = (const float*)d_in[20];
    const float* dense_W      = (const float*)d_in[21];
    const float* dense_b      = (const float*)d_in[22];

    // ws layout (floats): enc [64][512][256] | Qp 32768 f4 | Rp 32768 f4 | Wip 98304 f4 | Whp 98304 f4
    float*  enc = (float*)d_ws;
    float4* Qp  = (float4*)(enc + (size_t)Bsz * TH * Hh);
    float4* Rp  = Qp + 32768;
    float4* Wip = Rp + 32768;
    float4* Whp = Wip + 98304;

    hipMemsetAsync(enc, 0, (size_t)Bsz * TH * Hh * sizeof(float), stream);
    pack_k<<<384, 256, 0, stream>>>(Q, R, Wih_f, Whh_f, Wih_b, Whh_b, Qp, Rp, Wip, Whp);
    scan_k<<<64, 512, 0, stream>>>(sents, lens, emb,
                                   bih_f, bhh_f, bih_b, bhh_b,
                                   Qp, Rp, Wip, Whp, enc);
    epi_k<<<64, 256, 0, stream>>>(enc, entities, slices, slice_lens,
                                  entity_masks, slice_masks, ent_W, ent_b,
                                  att_w, dense_W, dense_b, (float*)d_out);
}